// Round 1
// baseline (219.700 us; speedup 1.0000x reference)
//
#include <hip/hip_runtime.h>
#include <math.h>

// AdderNet fused forward: 4096 images, one block per image, whole net in LDS.
//
// Shapes: x[4096,1,28,28] -> L1(w1[16,1,3,3],s2,p0) -> [16,13,13]
//         -> L2(w2[32,16,3,3],s2,p1) -> [32,7,7]
//         -> L3(w3[16,32,3,3],s2,p1) -> [16,4,4]
//         -> L4(w4[10,16,3,3],s2,p0) -> [10] -> log_softmax
//
// adder2d: out[o,i,j] = -sum_p |patch[p,i,j] - w[o,p]|, p = c*9+kh*3+kw.
//
// LDS plan (floats):
//  s_w23[4608] : w2 transposed [p=144][o=32] (stages 0-2), then w3 transposed
//                [p=288][o=16] (stage 3)
//  s_a1[3904]  : L1 out, padded [c=16][plane=244] (15 rows x stride 16, +4 pad
//                to de-conflict plane stride). After stage 2: red[1024]@0,
//                a3[256]@1024, logits[16]@1280, w4[1440]@1296.
//  s_a2[3456]  : xin[784]@0 + w1[144]@784 (stages 0-1), then L2 out padded
//                [c=32][r=9][stride=12] (stages 2-3).
// Total 11968 floats = 46.75 KB -> 3 blocks/CU.

__global__ __launch_bounds__(256, 3) void adder_net_kernel(
    const float* __restrict__ gx,
    const float* __restrict__ gw1,
    const float* __restrict__ gw2,
    const float* __restrict__ gw3,
    const float* __restrict__ gw4,
    float* __restrict__ gout)
{
  __shared__ __align__(16) float s_w23[4608];
  __shared__ __align__(16) float s_a1[3904];
  __shared__ __align__(16) float s_a2[3456];

  const int t = threadIdx.x;
  const int b = blockIdx.x;

  // ---------------- stage 0: staging ----------------
  // w2 transposed: s_w23[p*32+o] = w2[o*144+p]
  for (int k = t; k < 4608; k += 256) {
    int o = k / 144, p = k - o * 144;
    s_w23[p * 32 + o] = gw2[k];
  }
  // input image, minus 0.5, as float4
  {
    const float4* xv = (const float4*)(gx + (size_t)b * 784);
    float4* dv = (float4*)s_a2;
    for (int k = t; k < 196; k += 256) {
      float4 v = xv[k];
      v.x -= 0.5f; v.y -= 0.5f; v.z -= 0.5f; v.w -= 0.5f;
      dv[k] = v;
    }
  }
  // w1 into s_a2[784..927]
  for (int k = t; k < 144; k += 256) s_a2[784 + k] = gw1[k];
  // zero a1 (establishes pad=1 borders for layer 2)
  for (int k = t; k < 3904; k += 256) s_a1[k] = 0.0f;
  __syncthreads();

  // ---------------- stage 1: L1  [16,13,13] ----------------
  // t = i*16 + o  (o in low bits -> weight reads bank-spread, act reads
  // near-uniform across the o-lanes)
  if (t < 208) {
    const int o = t & 15;
    const int i = t >> 4;  // 0..12
    float acc[13];
#pragma unroll
    for (int j = 0; j < 13; ++j) acc[j] = 0.0f;
#pragma unroll
    for (int kh = 0; kh < 3; ++kh) {
      float row[28];
      const float* rp = s_a2 + (2 * i + kh) * 28;
#pragma unroll
      for (int q = 0; q < 7; ++q) {
        float4 v = *(const float4*)(rp + 4 * q);
        row[4 * q + 0] = v.x; row[4 * q + 1] = v.y;
        row[4 * q + 2] = v.z; row[4 * q + 3] = v.w;
      }
      const float* wp = s_a2 + 784 + o * 9 + kh * 3;
      const float w0 = wp[0], w1 = wp[1], w2 = wp[2];
#pragma unroll
      for (int j = 0; j < 13; ++j)
        acc[j] += fabsf(row[2 * j] - w0) + fabsf(row[2 * j + 1] - w1) +
                  fabsf(row[2 * j + 2] - w2);
    }
    float* ap = s_a1 + o * 244 + (i + 1) * 16 + 1;  // padded store
#pragma unroll
    for (int j = 0; j < 13; ++j)
      ap[j] = fmaxf((10.0f - acc[j]) * 0.25f, 0.0f);
  }
  __syncthreads();

  // zero a2 region (pad borders for layer 3) — xin/w1 are dead now
  for (int k = t; k < 3456; k += 256) s_a2[k] = 0.0f;
  __syncthreads();

  // ---------------- stage 2: L2  [32,7,7] ----------------
  // t = i*32 + o : lanes differ in o -> transposed weight reads conflict-free,
  // act row reads have 2 distinct addresses per wave (broadcast).
  if (t < 224) {
    const int o = t & 31;
    const int i = t >> 5;  // 0..6
    float acc[7];
#pragma unroll
    for (int j = 0; j < 7; ++j) acc[j] = 0.0f;
    for (int c = 0; c < 16; ++c) {
      const float* plane = s_a1 + c * 244;
#pragma unroll
      for (int kh = 0; kh < 3; ++kh) {
        float row[16];
        const float* rp = plane + (2 * i + kh) * 16;
#pragma unroll
        for (int q = 0; q < 4; ++q) {
          float4 v = *(const float4*)(rp + 4 * q);
          row[4 * q + 0] = v.x; row[4 * q + 1] = v.y;
          row[4 * q + 2] = v.z; row[4 * q + 3] = v.w;
        }
        const int pbase = c * 9 + kh * 3;
        const float w0 = s_w23[(pbase + 0) * 32 + o];
        const float w1 = s_w23[(pbase + 1) * 32 + o];
        const float w2 = s_w23[(pbase + 2) * 32 + o];
#pragma unroll
        for (int j = 0; j < 7; ++j)
          acc[j] += fabsf(row[2 * j] - w0) + fabsf(row[2 * j + 1] - w1) +
                    fabsf(row[2 * j + 2] - w2);
      }
    }
    float* ap = s_a2 + o * 108 + (i + 1) * 12 + 1;  // padded store
#pragma unroll
    for (int j = 0; j < 7; ++j)
      ap[j] = fmaxf((130.0f - acc[j]) * 0.125f, 0.0f);
  }
  __syncthreads();

  // restage: w3 transposed into s_w23, w4 into s_a1[1296..]
  for (int k = t; k < 4608; k += 256) {
    int o = k / 288, p = k - o * 288;
    s_w23[p * 16 + o] = gw3[k];
  }
  for (int k = t; k < 1440; k += 256) s_a1[1296 + k] = gw4[k];
  __syncthreads();

  // ---------------- stage 3: L3  [16,4,4] ----------------
  // t: o = t&15, i = (t>>4)&3, cg = t>>6 (channel-group split, 8 ch each)
  {
    const int o = t & 15;
    const int i = (t >> 4) & 3;
    const int cg = t >> 6;
    float acc[4];
#pragma unroll
    for (int j = 0; j < 4; ++j) acc[j] = 0.0f;
    for (int k = 0; k < 8; ++k) {
      const int c = cg * 8 + k;
      const float* plane = s_a2 + c * 108;
#pragma unroll
      for (int kh = 0; kh < 3; ++kh) {
        const float* rp = plane + (2 * i + kh) * 12;
        float row[9];
        float4 v0 = *(const float4*)(rp);
        float4 v1 = *(const float4*)(rp + 4);
        row[0] = v0.x; row[1] = v0.y; row[2] = v0.z; row[3] = v0.w;
        row[4] = v1.x; row[5] = v1.y; row[6] = v1.z; row[7] = v1.w;
        row[8] = rp[8];
        const int pbase = c * 9 + kh * 3;
        const float w0 = s_w23[(pbase + 0) * 16 + o];
        const float w1 = s_w23[(pbase + 1) * 16 + o];
        const float w2 = s_w23[(pbase + 2) * 16 + o];
#pragma unroll
        for (int j = 0; j < 4; ++j)
          acc[j] += fabsf(row[2 * j] - w0) + fabsf(row[2 * j + 1] - w1) +
                    fabsf(row[2 * j + 2] - w2);
      }
    }
    // red[cg][o][i][j] @ s_a1[0..1023]
#pragma unroll
    for (int j = 0; j < 4; ++j)
      s_a1[cg * 256 + o * 16 + i * 4 + j] = acc[j];
  }
  __syncthreads();
  {
    // reduce channel groups, apply activation -> a3[o*16+ij] @ s_a1[1024..]
    float s = s_a1[t] + s_a1[256 + t] + s_a1[512 + t] + s_a1[768 + t];
    s_a1[1024 + t] = fmaxf((280.0f - s) * 0.0625f, 0.0f);
  }
  __syncthreads();

  // ---------------- stage 4: L4 logits + log_softmax ----------------
  if (t < 160) {
    const int o = t >> 4;   // 0..9
    const int c = t & 15;
    const float* a3 = s_a1 + 1024 + c * 16;          // [4][4], patch rows 0..2
    const float* wp = s_a1 + 1296 + o * 144 + c * 9; // w4
    float partial = 0.0f;
#pragma unroll
    for (int kh = 0; kh < 3; ++kh)
#pragma unroll
      for (int kw = 0; kw < 3; ++kw)
        partial += fabsf(a3[kh * 4 + kw] - wp[kh * 3 + kw]);
    s_a1[t] = partial;  // red2 @ s_a1[0..159] (red region dead)
  }
  __syncthreads();
  if (t < 10) {
    float s = 0.0f;
#pragma unroll
    for (int c = 0; c < 16; ++c) s += s_a1[t * 16 + c];
    s_a1[1280 + t] = -s;  // logits
  }
  __syncthreads();
  if (t < 10) {
    float m = -1e30f;
#pragma unroll
    for (int k = 0; k < 10; ++k) m = fmaxf(m, s_a1[1280 + k]);
    float sum = 0.0f;
#pragma unroll
    for (int k = 0; k < 10; ++k) sum += __expf(s_a1[1280 + k] - m);
    gout[b * 10 + t] = s_a1[1280 + t] - m - __logf(sum);
  }
}

extern "C" void kernel_launch(void* const* d_in, const int* in_sizes, int n_in,
                              void* d_out, int out_size, void* d_ws, size_t ws_size,
                              hipStream_t stream) {
  const float* x  = (const float*)d_in[0];
  const float* w1 = (const float*)d_in[1];
  const float* w2 = (const float*)d_in[2];
  const float* w3 = (const float*)d_in[3];
  const float* w4 = (const float*)d_in[4];
  float* out = (float*)d_out;
  adder_net_kernel<<<4096, 256, 0, stream>>>(x, w1, w2, w3, w4, out);
}

// Round 2
// 122.718 us; speedup vs baseline: 1.7903x; 1.7903x over previous
//
#include <hip/hip_runtime.h>
#include <math.h>

// AdderNet fused forward, u16 fixed-point + v_sad_u16 (2 terms + acc / instr).
//
// Quantization: q(v) = round((v+8)*1024) as u16. Shared affine transform =>
// |q(a)-q(w)| = 1024*|a-w| (+-1 rounding). SAD accumulates exactly in u32.
// Zero-padding cells hold q(0) = 0x2000 (word 0x20002000).
//
// 2 images per block, 2048 blocks. Channel-paired words everywhere:
// act word (y,x) = (a[2m,y,x], a[2m+1,y,x]); weight word = (w[o,2m,..], w[o,2m+1,..]).
//
// LDS (uint words, 46.6 KB total -> 3 blocks/CU):
//  s_w[2304] : WP2[m8][kh3][kw3][o32], restaged to WP3[m16][kh][kw][o16]
//  s_a1[4800]: A1[m8][img2][y15][x20] (x-stride 20 => row quads hit disjoint banks)
//  s_a2[3456]: stages 0-1: X[img2][y28][x-stride20]; then A2[img2][m16][y9][x12]
//  s_sm[1104]: W1[96]@0 ([o16][kh3][pr2], pr1 hi=0), W4[720]@96 ([m8][pk9][o10]),
//              A3[256]@816, logits(float)@1072

#if defined(__has_builtin)
#if __has_builtin(__builtin_amdgcn_sad_u16)
#define HAS_SAD 1
#endif
#endif

__device__ __forceinline__ unsigned sadu16(unsigned a, unsigned b, unsigned acc) {
#ifdef HAS_SAD
  return __builtin_amdgcn_sad_u16(a, b, acc);
#else
  int al = (int)(a & 0xFFFFu), ah = (int)(a >> 16);
  int bl = (int)(b & 0xFFFFu), bh = (int)(b >> 16);
  return acc + (unsigned)(al > bl ? al - bl : bl - al)
             + (unsigned)(ah > bh ? ah - bh : bh - ah);
#endif
}

__device__ __forceinline__ unsigned quant(float v) {
  return (unsigned)fmaf(v, 1024.0f, 8192.5f);  // v >= -8 by construction
}

#define QPAD 0x20002000u

__global__ __launch_bounds__(256, 3) void adder_net_kernel(
    const float* __restrict__ gx,
    const float* __restrict__ gw1,
    const float* __restrict__ gw2,
    const float* __restrict__ gw3,
    const float* __restrict__ gw4,
    float* __restrict__ gout)
{
  __shared__ __align__(16) unsigned s_w[2304];
  __shared__ __align__(16) unsigned s_a1[4800];
  __shared__ __align__(16) unsigned s_a2[3456];
  __shared__ __align__(16) unsigned s_sm[1104];

  const int t = threadIdx.x;
  const int b = blockIdx.x;

  // ---------------- stage 0: staging + quantization ----------------
  // X: (x - 0.5) quantized, word = (x[2k], x[2k+1]); layout [img][y][stride 20]
  for (int k = t; k < 784; k += 256) {
    int img = (k >= 392) ? 1 : 0;
    int r = k - img * 392;
    int y = r / 14, xw = r - y * 14;
    const float* px = gx + (size_t)(2 * b + img) * 784 + y * 28 + 2 * xw;
    float2 v = *(const float2*)px;
    s_a2[img * 560 + y * 20 + xw] = quant(v.x - 0.5f) | (quant(v.y - 0.5f) << 16);
  }
  // WP2[m][kh][kw][o32]: word k = ((m*3+kh)*3+kw)*32 + o
  for (int k = t; k < 2304; k += 256) {
    int o = k & 31, r = k >> 5;          // r = m*9 + pk
    int m = r / 9, pk = r - m * 9;
    int base = o * 144 + 2 * m * 9 + pk;
    s_w[k] = quant(gw2[base]) | (quant(gw2[base + 9]) << 16);
  }
  // W1[o][kh][pr]: pr0 = (w0,w1), pr1 = (w2, 0)
  if (t < 96) {
    int pr = t & 1, r = t >> 1;          // r = o*3 + kh
    int o = r / 3, kh = r - o * 3;
    const float* pw = gw1 + o * 9 + kh * 3;
    s_sm[t] = pr ? quant(pw[2]) : (quant(pw[0]) | (quant(pw[1]) << 16));
  }
  // W4[m][pk][o10]
  for (int k = t; k < 720; k += 256) {
    int o = k % 10, r = k / 10;          // r = m*9 + pk
    int m = r / 9, pk = r - m * 9;
    int base = o * 144 + 2 * m * 9 + pk;
    s_sm[96 + k] = quant(gw4[base]) | (quant(gw4[base + 9]) << 16);
  }
  // A1 <- q(0) everywhere (borders for L2's padding=1)
  {
    uint4 pad4 = make_uint4(QPAD, QPAD, QPAD, QPAD);
    uint4* p = (uint4*)s_a1;
    for (int k = t; k < 1200; k += 256) p[k] = pad4;
  }
  __syncthreads();

  // ---------------- stage 1: L1 [16,13,13] ----------------
  if (t < 208) {
    const int img = t & 1;
    const int op  = (t >> 1) & 7;        // output-channel pair
    const int i   = t >> 4;              // 0..12
    unsigned acc0[13], acc1[13];
#pragma unroll
    for (int j = 0; j < 13; ++j) { acc0[j] = 0u; acc1[j] = 0u; }
    const unsigned* w1a = s_sm + (2 * op) * 6;
    const unsigned* w1b = s_sm + (2 * op + 1) * 6;
#pragma unroll
    for (int kh = 0; kh < 3; ++kh) {
      const unsigned* row = s_a2 + img * 560 + (2 * i + kh) * 20;
      uint4 v0 = *(const uint4*)(row);
      uint4 v1 = *(const uint4*)(row + 4);
      uint4 v2 = *(const uint4*)(row + 8);
      uint2 v3 = *(const uint2*)(row + 12);
      unsigned r[14] = {v0.x, v0.y, v0.z, v0.w, v1.x, v1.y, v1.z, v1.w,
                        v2.x, v2.y, v2.z, v2.w, v3.x, v3.y};
      const unsigned wa01 = w1a[kh * 2], wa2 = w1a[kh * 2 + 1];
      const unsigned wb01 = w1b[kh * 2], wb2 = w1b[kh * 2 + 1];
#pragma unroll
      for (int j = 0; j < 13; ++j) {
        unsigned mw = r[j + 1] & 0xFFFFu;      // (x[2j+2], 0)
        acc0[j] = sadu16(r[j], wa01, acc0[j]);
        acc0[j] = sadu16(mw, wa2, acc0[j]);
        acc1[j] = sadu16(r[j], wb01, acc1[j]);
        acc1[j] = sadu16(mw, wb2, acc1[j]);
      }
    }
    unsigned* dst = s_a1 + op * 600 + img * 300 + (i + 1) * 20 + 1;
#pragma unroll
    for (int j = 0; j < 13; ++j) {
      float f0 = fmaxf(fmaf((float)acc0[j], -1.0f / 4096.0f, 2.5f), 0.0f);
      float f1 = fmaxf(fmaf((float)acc1[j], -1.0f / 4096.0f, 2.5f), 0.0f);
      dst[j] = quant(f0) | (quant(f1) << 16);
    }
  }
  __syncthreads();

  // ---------------- stage 2: L2 [32,7,7] ----------------
  // A2 border cells <- q(0)  (X is dead now; same barrier interval as compute)
  for (int k = t; k < 1024; k += 256) {
    int plane = k >> 5, c = k & 31;
    int y, x;
    if (c < 9)       { y = 0; x = c; }
    else if (c < 18) { y = 8; x = c - 9; }
    else if (c < 25) { y = c - 17; x = 0; }
    else             { y = c - 24; x = 8; }
    s_a2[plane * 108 + y * 12 + x] = QPAD;
  }
  if (t < 224) {
    const int img = t & 1;
    const int op  = (t >> 1) & 15;
    const int i   = t >> 5;              // 0..6
    unsigned acc0[7], acc1[7];
#pragma unroll
    for (int j = 0; j < 7; ++j) { acc0[j] = 0u; acc1[j] = 0u; }
#pragma unroll
    for (int m = 0; m < 8; ++m) {
#pragma unroll
      for (int kh = 0; kh < 3; ++kh) {
        const unsigned* row = s_a1 + m * 600 + img * 300 + (2 * i + kh) * 20;
        uint4 v0 = *(const uint4*)(row);
        uint4 v1 = *(const uint4*)(row + 4);
        uint4 v2 = *(const uint4*)(row + 8);
        uint4 v3 = *(const uint4*)(row + 12);
        unsigned r[16] = {v0.x, v0.y, v0.z, v0.w, v1.x, v1.y, v1.z, v1.w,
                          v2.x, v2.y, v2.z, v2.w, v3.x, v3.y, v3.z, v3.w};
        const unsigned* wp = s_w + (m * 3 + kh) * 96 + 2 * op;
        uint2 W0 = *(const uint2*)(wp);
        uint2 W1 = *(const uint2*)(wp + 32);
        uint2 W2 = *(const uint2*)(wp + 64);
#pragma unroll
        for (int j = 0; j < 7; ++j) {
          acc0[j] = sadu16(r[2 * j],     W0.x, acc0[j]);
          acc0[j] = sadu16(r[2 * j + 1], W1.x, acc0[j]);
          acc0[j] = sadu16(r[2 * j + 2], W2.x, acc0[j]);
          acc1[j] = sadu16(r[2 * j],     W0.y, acc1[j]);
          acc1[j] = sadu16(r[2 * j + 1], W1.y, acc1[j]);
          acc1[j] = sadu16(r[2 * j + 2], W2.y, acc1[j]);
        }
      }
    }
    unsigned* dst = s_a2 + ((img * 16 + op) * 9 + i + 1) * 12 + 1;
#pragma unroll
    for (int j = 0; j < 7; ++j) {
      float f0 = fmaxf(fmaf((float)acc0[j], -1.0f / 8192.0f, 16.25f), 0.0f);
      float f1 = fmaxf(fmaf((float)acc1[j], -1.0f / 8192.0f, 16.25f), 0.0f);
      dst[j] = quant(f0) | (quant(f1) << 16);
    }
  }
  __syncthreads();

  // restage W3 -> WP3[m16][kh][kw][o16]: word k = (m2*9+pk)*16 + o
  for (int k = t; k < 2304; k += 256) {
    int o = k & 15, r = k >> 4;          // r = m2*9 + pk
    int m2 = r / 9, pk = r - m2 * 9;
    int base = o * 288 + 2 * m2 * 9 + pk;
    s_w[k] = quant(gw3[base]) | (quant(gw3[base + 9]) << 16);
  }
  __syncthreads();

  // ---------------- stage 3: L3 [16,4,4] ----------------
  {
    const int img = t & 1;
    const int op  = (t >> 1) & 7;
    const int i   = (t >> 4) & 3;
    const int j   = t >> 6;              // 0..3
    unsigned acc0 = 0u, acc1 = 0u;
#pragma unroll
    for (int m2 = 0; m2 < 16; ++m2) {
#pragma unroll
      for (int kh = 0; kh < 3; ++kh) {
        const unsigned* row = s_a2 + ((img * 16 + m2) * 9 + 2 * i + kh) * 12 + 2 * j;
        uint2 A01 = *(const uint2*)row;
        unsigned A2w = row[2];
        const unsigned* wp = s_w + (m2 * 3 + kh) * 48 + 2 * op;
        uint2 K0 = *(const uint2*)(wp);
        uint2 K1 = *(const uint2*)(wp + 16);
        uint2 K2 = *(const uint2*)(wp + 32);
        acc0 = sadu16(A01.x, K0.x, acc0);
        acc0 = sadu16(A01.y, K1.x, acc0);
        acc0 = sadu16(A2w,  K2.x, acc0);
        acc1 = sadu16(A01.x, K0.y, acc1);
        acc1 = sadu16(A01.y, K1.y, acc1);
        acc1 = sadu16(A2w,  K2.y, acc1);
      }
    }
    float f0 = fmaxf(fmaf((float)acc0, -1.0f / 16384.0f, 17.5f), 0.0f);
    float f1 = fmaxf(fmaf((float)acc1, -1.0f / 16384.0f, 17.5f), 0.0f);
    s_sm[816 + ((img * 8 + op) * 4 + i) * 4 + j] = quant(f0) | (quant(f1) << 16);
  }
  __syncthreads();

  // ---------------- stage 4: L4 + log_softmax ----------------
  if (t < 160) {
    int o = t % 10, g = t / 10;          // g = m*2 + img
    int img = g & 1, m = g >> 1;
    const unsigned* a3 = s_sm + 816 + (img * 8 + m) * 16;
    const unsigned* w4 = s_sm + 96 + m * 90;
    unsigned acc = 0u;
#pragma unroll
    for (int kh = 0; kh < 3; ++kh)
#pragma unroll
      for (int kw = 0; kw < 3; ++kw)
        acc = sadu16(a3[kh * 4 + kw], w4[(kh * 3 + kw) * 10 + o], acc);
    s_a1[t] = acc;                        // partial at [(m*2+img)*10 + o]
  }
  __syncthreads();
  if (t < 20) {
    int o = t % 10, img = t / 10;
    unsigned s = 0u;
#pragma unroll
    for (int m = 0; m < 8; ++m) s += s_a1[(m * 2 + img) * 10 + o];
    ((float*)s_sm)[1072 + img * 10 + o] = -(float)s * (1.0f / 1024.0f);
  }
  __syncthreads();
  if (t < 20) {
    int o = t % 10, img = t / 10;
    const float* lg = (const float*)s_sm + 1072 + img * 10;
    float mx = lg[0];
#pragma unroll
    for (int k = 1; k < 10; ++k) mx = fmaxf(mx, lg[k]);
    float sum = 0.0f;
#pragma unroll
    for (int k = 0; k < 10; ++k) sum += __expf(lg[k] - mx);
    gout[(size_t)(2 * b + img) * 10 + o] = lg[o] - mx - __logf(sum);
  }
}

extern "C" void kernel_launch(void* const* d_in, const int* in_sizes, int n_in,
                              void* d_out, int out_size, void* d_ws, size_t ws_size,
                              hipStream_t stream) {
  const float* x  = (const float*)d_in[0];
  const float* w1 = (const float*)d_in[1];
  const float* w2 = (const float*)d_in[2];
  const float* w3 = (const float*)d_in[3];
  const float* w4 = (const float*)d_in[4];
  float* out = (float*)d_out;
  adder_net_kernel<<<2048, 256, 0, stream>>>(x, w1, w2, w3, w4, out);
}

// Round 3
// 120.540 us; speedup vs baseline: 1.8226x; 1.0181x over previous
//
#include <hip/hip_runtime.h>
#include <math.h>

// AdderNet fused forward, u16 fixed-point + v_sad_u16, 4-output/thread blocking.
//
// q(v) = round((v+8)*1024) u16; |q(a)-q(w)| = 1024*|a-w| (+-1). Pad = q(0).
// Words pair adjacent channels: act(y,x)=(a[2m],a[2m+1]); w word=(w[o,2m],w[o,2m+1]).
//
// 2 images/block, 2048 blocks, 256 threads, 4 blocks/CU (LDS 40,192 B).
//
// LDS (uint words):
//  s_w[2304]  : WP2 [m8][kh3][q8][kw3*4+u]  ->  WP3 [m16][kh3][q4][kw3*4+u]
//  s_a1[4800] : A1 [plane16=(m*2+img)][row15*20] (stages 0-2)
//               then W4[720]@0, partials[2048]@720, A3[256]@2768,
//               L4partials[160]@3040, logits(float)[20]@3200
//  s_a2[2944] : X[img2][560]@0 + W1[96]@1120 (stages 0-1)
//               then A2 [plane32=(img*16+m2)][92] (rows stride 10)

#if defined(__has_builtin)
#if __has_builtin(__builtin_amdgcn_sad_u16)
#define HAS_SAD 1
#endif
#endif

__device__ __forceinline__ unsigned sadu16(unsigned a, unsigned b, unsigned acc) {
#ifdef HAS_SAD
  return __builtin_amdgcn_sad_u16(a, b, acc);
#else
  int al = (int)(a & 0xFFFFu), ah = (int)(a >> 16);
  int bl = (int)(b & 0xFFFFu), bh = (int)(b >> 16);
  return acc + (unsigned)(al > bl ? al - bl : bl - al)
             + (unsigned)(ah > bh ? ah - bh : bh - ah);
#endif
}

__device__ __forceinline__ unsigned quant(float v) {
  return (unsigned)fmaf(v, 1024.0f, 8192.5f);  // v >= -8 by construction
}

#define QPAD 0x20002000u

__global__ __launch_bounds__(256, 4) void adder_net_kernel(
    const float* __restrict__ gx,
    const float* __restrict__ gw1,
    const float* __restrict__ gw2,
    const float* __restrict__ gw3,
    const float* __restrict__ gw4,
    float* __restrict__ gout)
{
  __shared__ __align__(16) unsigned s_w[2304];
  __shared__ __align__(16) unsigned s_a1[4800];
  __shared__ __align__(16) unsigned s_a2[2944];

  const int t = threadIdx.x;
  const int b = blockIdx.x;

  // ---------------- stage 0: staging + quantization ----------------
  for (int k = t; k < 784; k += 256) {
    int img = (k >= 392) ? 1 : 0;
    int r = k - img * 392;
    int y = r / 14, xw = r - y * 14;
    const float* px = gx + (size_t)(2 * b + img) * 784 + y * 28 + 2 * xw;
    float2 v = *(const float2*)px;
    s_a2[img * 560 + y * 20 + xw] = quant(v.x - 0.5f) | (quant(v.y - 0.5f) << 16);
  }
  // WP2: idx = ((m*3+kh)*8+q)*12 + kw*4 + u ; o = q*4+u
  for (int k = t; k < 2304; k += 256) {
    int g = k / 12, r = k - g * 12;
    int m = g / 24, g2 = g - m * 24, kh = g2 >> 3, q = g2 & 7;
    int kw = r >> 2, u = r & 3, o = q * 4 + u;
    int base = o * 144 + 2 * m * 9 + kh * 3 + kw;
    s_w[k] = quant(gw2[base]) | (quant(gw2[base + 9]) << 16);
  }
  // W1 [op8][12]: per op: ch-a 6 words (kh x {pair01, (w2,0)}), then ch-b 6
  if (t < 96) {
    int op = t / 12, idx = t - op * 12;
    int ch = idx / 6, w = idx - ch * 6, kh = w >> 1, half = w & 1;
    const float* pw = gw1 + (op * 2 + ch) * 9 + kh * 3;
    s_a2[1120 + t] = half ? quant(pw[2]) : (quant(pw[0]) | (quant(pw[1]) << 16));
  }
  // zero A1 (borders for L2 padding=1)
  {
    uint4 pad4 = make_uint4(QPAD, QPAD, QPAD, QPAD);
    uint4* p = (uint4*)s_a1;
    for (int k = t; k < 1200; k += 256) p[k] = pad4;
  }
  __syncthreads();

  // ---------------- stage 1: L1 [16,13,13] ----------------
  if (t < 208) {
    const int img = t & 1;
    const int op  = (t >> 1) & 7;
    const int i   = t >> 4;  // 0..12
    unsigned acc0[13], acc1[13];
#pragma unroll
    for (int j = 0; j < 13; ++j) { acc0[j] = 0u; acc1[j] = 0u; }
    const unsigned* Wp = s_a2 + 1120 + op * 12;
    uint4 Wa = ((const uint4*)Wp)[0];
    uint4 Wb = ((const uint4*)Wp)[1];
    uint4 Wc = ((const uint4*)Wp)[2];
    unsigned wv[12] = {Wa.x, Wa.y, Wa.z, Wa.w, Wb.x, Wb.y, Wb.z, Wb.w,
                       Wc.x, Wc.y, Wc.z, Wc.w};
#pragma unroll
    for (int kh = 0; kh < 3; ++kh) {
      const unsigned* rp = s_a2 + img * 560 + (2 * i + kh) * 20;
      uint4 v0 = *(const uint4*)(rp);
      uint4 v1 = *(const uint4*)(rp + 4);
      uint4 v2 = *(const uint4*)(rp + 8);
      uint2 v3 = *(const uint2*)(rp + 12);
      unsigned r[14] = {v0.x, v0.y, v0.z, v0.w, v1.x, v1.y, v1.z, v1.w,
                        v2.x, v2.y, v2.z, v2.w, v3.x, v3.y};
      const unsigned wa01 = wv[kh * 2], wa2 = wv[kh * 2 + 1];
      const unsigned wb01 = wv[6 + kh * 2], wb2 = wv[6 + kh * 2 + 1];
#pragma unroll
      for (int j = 0; j < 13; ++j) {
        unsigned mw = r[j + 1] & 0xFFFFu;
        acc0[j] = sadu16(r[j], wa01, acc0[j]);
        acc0[j] = sadu16(mw, wa2, acc0[j]);
        acc1[j] = sadu16(r[j], wb01, acc1[j]);
        acc1[j] = sadu16(mw, wb2, acc1[j]);
      }
    }
    unsigned* dst = s_a1 + (op * 2 + img) * 300 + (i + 1) * 20 + 1;
#pragma unroll
    for (int j = 0; j < 13; ++j) {
      float f0 = fmaxf(fmaf((float)acc0[j], -1.0f / 4096.0f, 2.5f), 0.0f);
      float f1 = fmaxf(fmaf((float)acc1[j], -1.0f / 4096.0f, 2.5f), 0.0f);
      dst[j] = quant(f0) | (quant(f1) << 16);
    }
  }
  __syncthreads();

  // ---------------- stage 2: L2 [32,7,7], 4 outputs/thread ----------------
  if (t < 112) {
    const int img = t & 1;
    const int q   = (t >> 1) & 7;   // output quad: o = 4q..4q+3
    const int i   = t >> 4;         // 0..6
    unsigned acc[4][7];
#pragma unroll
    for (int u = 0; u < 4; ++u)
#pragma unroll
      for (int j = 0; j < 7; ++j) acc[u][j] = 0u;
    for (int m = 0; m < 8; ++m) {
      const unsigned* plane = s_a1 + (m * 2 + img) * 300;
      const unsigned* wg = s_w + m * 288 + q * 12;
#pragma unroll
      for (int kh = 0; kh < 3; ++kh) {
        const unsigned* rp = plane + (2 * i + kh) * 20;
        uint4 v0 = *(const uint4*)(rp);
        uint4 v1 = *(const uint4*)(rp + 4);
        uint4 v2 = *(const uint4*)(rp + 8);
        uint4 v3 = *(const uint4*)(rp + 12);
        unsigned r[16] = {v0.x, v0.y, v0.z, v0.w, v1.x, v1.y, v1.z, v1.w,
                          v2.x, v2.y, v2.z, v2.w, v3.x, v3.y, v3.z, v3.w};
        uint4 W0 = *(const uint4*)(wg + kh * 96);
        uint4 W1 = *(const uint4*)(wg + kh * 96 + 4);
        uint4 W2 = *(const uint4*)(wg + kh * 96 + 8);
#pragma unroll
        for (int j = 0; j < 7; ++j) {
          acc[0][j] = sadu16(r[2 * j],     W0.x, acc[0][j]);
          acc[0][j] = sadu16(r[2 * j + 1], W1.x, acc[0][j]);
          acc[0][j] = sadu16(r[2 * j + 2], W2.x, acc[0][j]);
          acc[1][j] = sadu16(r[2 * j],     W0.y, acc[1][j]);
          acc[1][j] = sadu16(r[2 * j + 1], W1.y, acc[1][j]);
          acc[1][j] = sadu16(r[2 * j + 2], W2.y, acc[1][j]);
          acc[2][j] = sadu16(r[2 * j],     W0.z, acc[2][j]);
          acc[2][j] = sadu16(r[2 * j + 1], W1.z, acc[2][j]);
          acc[2][j] = sadu16(r[2 * j + 2], W2.z, acc[2][j]);
          acc[3][j] = sadu16(r[2 * j],     W0.w, acc[3][j]);
          acc[3][j] = sadu16(r[2 * j + 1], W1.w, acc[3][j]);
          acc[3][j] = sadu16(r[2 * j + 2], W2.w, acc[3][j]);
        }
      }
    }
    unsigned* d0 = s_a2 + (img * 16 + 2 * q) * 92 + (i + 1) * 10 + 1;
#pragma unroll
    for (int j = 0; j < 7; ++j) {
      float f0 = fmaxf(fmaf((float)acc[0][j], -1.0f / 8192.0f, 16.25f), 0.0f);
      float f1 = fmaxf(fmaf((float)acc[1][j], -1.0f / 8192.0f, 16.25f), 0.0f);
      float f2 = fmaxf(fmaf((float)acc[2][j], -1.0f / 8192.0f, 16.25f), 0.0f);
      float f3 = fmaxf(fmaf((float)acc[3][j], -1.0f / 8192.0f, 16.25f), 0.0f);
      d0[j]      = quant(f0) | (quant(f1) << 16);
      d0[92 + j] = quant(f2) | (quant(f3) << 16);
    }
  } else {
    // A2 border cells <- q(0), done by the otherwise-idle threads
    for (int k = t - 112; k < 1024; k += 144) {
      int plane = k >> 5, c = k & 31;
      int y, x;
      if (c < 9)       { y = 0; x = c; }
      else if (c < 18) { y = 8; x = c - 9; }
      else if (c < 25) { y = c - 17; x = 0; }
      else             { y = c - 24; x = 8; }
      s_a2[plane * 92 + y * 10 + x] = QPAD;
    }
  }
  __syncthreads();

  // restage: WP3 idx = ((m2*3+kh)*4+q)*12 + kw*4 + u ; o = q*4+u
  for (int k = t; k < 2304; k += 256) {
    int g = k / 12, r = k - g * 12;
    int m2 = g / 12, g2 = g - m2 * 12, kh = g2 >> 2, q = g2 & 3;
    int kw = r >> 2, u = r & 3, o = q * 4 + u;
    int base = o * 288 + 2 * m2 * 9 + kh * 3 + kw;
    s_w[k] = quant(gw3[base]) | (quant(gw3[base + 9]) << 16);
  }
  // W4 [m8][pk9][o10] @ s_a1[0..719]
  for (int k = t; k < 720; k += 256) {
    int o = k % 10, r = k / 10, m = r / 9, pk = r - m * 9;
    int base = o * 144 + 2 * m * 9 + pk;
    s_a1[k] = quant(gw4[base]) | (quant(gw4[base + 9]) << 16);
  }
  __syncthreads();

  // ---------------- stage 3: L3 [16,4,4], 4 outs x 4 j /thread, mg4 split ----
  if (t < 128) {
    const int img = t & 1;
    const int q   = (t >> 1) & 3;   // o = 4q..4q+3
    const int i   = (t >> 3) & 3;
    const int mg  = t >> 5;         // channel-pair group: m2 = 4mg..4mg+3
    unsigned acc[4][4];
#pragma unroll
    for (int u = 0; u < 4; ++u)
#pragma unroll
      for (int j = 0; j < 4; ++j) acc[u][j] = 0u;
#pragma unroll
    for (int mm = 0; mm < 4; ++mm) {
      const int m2 = mg * 4 + mm;
      const unsigned* plane = s_a2 + (img * 16 + m2) * 92;
      const unsigned* wg = s_w + m2 * 144 + q * 12;
#pragma unroll
      for (int kh = 0; kh < 3; ++kh) {
        const unsigned* rp = plane + (2 * i + kh) * 10;
        uint2 a0 = *(const uint2*)(rp);
        uint2 a1 = *(const uint2*)(rp + 2);
        uint2 a2 = *(const uint2*)(rp + 4);
        uint2 a3 = *(const uint2*)(rp + 6);
        unsigned a8 = rp[8];
        unsigned r9[9] = {a0.x, a0.y, a1.x, a1.y, a2.x, a2.y, a3.x, a3.y, a8};
        uint4 W0 = *(const uint4*)(wg + kh * 48);
        uint4 W1 = *(const uint4*)(wg + kh * 48 + 4);
        uint4 W2 = *(const uint4*)(wg + kh * 48 + 8);
#pragma unroll
        for (int j = 0; j < 4; ++j) {
          acc[0][j] = sadu16(r9[2 * j],     W0.x, acc[0][j]);
          acc[0][j] = sadu16(r9[2 * j + 1], W1.x, acc[0][j]);
          acc[0][j] = sadu16(r9[2 * j + 2], W2.x, acc[0][j]);
          acc[1][j] = sadu16(r9[2 * j],     W0.y, acc[1][j]);
          acc[1][j] = sadu16(r9[2 * j + 1], W1.y, acc[1][j]);
          acc[1][j] = sadu16(r9[2 * j + 2], W2.y, acc[1][j]);
          acc[2][j] = sadu16(r9[2 * j],     W0.z, acc[2][j]);
          acc[2][j] = sadu16(r9[2 * j + 1], W1.z, acc[2][j]);
          acc[2][j] = sadu16(r9[2 * j + 2], W2.z, acc[2][j]);
          acc[3][j] = sadu16(r9[2 * j],     W0.w, acc[3][j]);
          acc[3][j] = sadu16(r9[2 * j + 1], W1.w, acc[3][j]);
          acc[3][j] = sadu16(r9[2 * j + 2], W2.w, acc[3][j]);
        }
      }
    }
    // partials: f = (img*16 + q*4 + u)*16 + i*4 + j ; store at 720 + mg*512 + f
    unsigned* pp = s_a1 + 720 + mg * 512 + (img * 16 + q * 4) * 16 + i * 4;
#pragma unroll
    for (int u = 0; u < 4; ++u)
      *(uint4*)(pp + u * 16) = make_uint4(acc[u][0], acc[u][1], acc[u][2], acc[u][3]);
  }
  __syncthreads();

  // reduce mg-groups -> A3 words (channel pairs) @ s_a1[2768..3023]
  {
    int w = t;
    int img = w >> 7, m = (w >> 4) & 7, pos = w & 15;
    int f0 = img * 256 + m * 32 + pos;   // out o=2m ; o=2m+1 at f0+16
    const unsigned* P = s_a1 + 720;
    unsigned s0 = P[f0] + P[512 + f0] + P[1024 + f0] + P[1536 + f0];
    unsigned s1 = P[f0 + 16] + P[512 + f0 + 16] + P[1024 + f0 + 16] + P[1536 + f0 + 16];
    float f0f = fmaxf(fmaf((float)s0, -1.0f / 16384.0f, 17.5f), 0.0f);
    float f1f = fmaxf(fmaf((float)s1, -1.0f / 16384.0f, 17.5f), 0.0f);
    s_a1[2768 + w] = quant(f0f) | (quant(f1f) << 16);
  }
  __syncthreads();

  // ---------------- stage 4: L4 + log_softmax ----------------
  if (t < 160) {
    int o = t % 10, g = t / 10, img = g & 1, m = g >> 1;
    const unsigned* a3 = s_a1 + 2768 + (img * 8 + m) * 16;
    const unsigned* w4 = s_a1 + m * 90;
    unsigned acc = 0u;
#pragma unroll
    for (int kh = 0; kh < 3; ++kh)
#pragma unroll
      for (int kw = 0; kw < 3; ++kw)
        acc = sadu16(a3[kh * 4 + kw], w4[(kh * 3 + kw) * 10 + o], acc);
    s_a1[3040 + t] = acc;
  }
  __syncthreads();
  if (t < 20) {
    int o = t % 10, img = t / 10;
    unsigned s = 0u;
#pragma unroll
    for (int m = 0; m < 8; ++m) s += s_a1[3040 + (m * 2 + img) * 10 + o];
    ((float*)s_a1)[3200 + img * 10 + o] = -(float)s * (1.0f / 1024.0f);
  }
  __syncthreads();
  if (t < 20) {
    int o = t % 10, img = t / 10;
    const float* lg = (const float*)s_a1 + 3200 + img * 10;
    float mx = lg[0];
#pragma unroll
    for (int k = 1; k < 10; ++k) mx = fmaxf(mx, lg[k]);
    float sum = 0.0f;
#pragma unroll
    for (int k = 0; k < 10; ++k) sum += __expf(lg[k] - mx);
    gout[(size_t)(2 * b + img) * 10 + o] = lg[o] - mx - __logf(sum);
  }
}

extern "C" void kernel_launch(void* const* d_in, const int* in_sizes, int n_in,
                              void* d_out, int out_size, void* d_ws, size_t ws_size,
                              hipStream_t stream) {
  const float* x  = (const float*)d_in[0];
  const float* w1 = (const float*)d_in[1];
  const float* w2 = (const float*)d_in[2];
  const float* w3 = (const float*)d_in[3];
  const float* w4 = (const float*)d_in[4];
  float* out = (float*)d_out;
  adder_net_kernel<<<2048, 256, 0, stream>>>(x, w1, w2, w3, w4, out);
}